// Round 10
// baseline (697.732 us; speedup 1.0000x reference)
//
#include <hip/hip_runtime.h>
#include <cmath>

#define N_NODES 100000
#define N_EDGES 1600000
#define F_IN 512
#define F_HID 128
#define F_OUT 64

// ---- bucketed CSR-build params ----
#define BK_SHIFT 10                        // 1024 nodes per bucket
#define NBUK ((N_NODES + 1023) >> 10)      // 98 buckets
#define SCAP 24576                         // staging capacity/bucket
#define LSLOT 64                           // LDS slots per bucket
#define NBLK_A 512                         // partition blocks (2/CU)
#define FILL_SPLIT 8                       // slice-blocks per bucket, disjoint node ranges
#define NPS (1024 / FILL_SPLIT)            // 128 nodes per slice
#define OV_CAP 4096                        // global overflow records

typedef __attribute__((ext_vector_type(8))) short short8;
typedef __attribute__((ext_vector_type(4))) float float4v;
typedef __attribute__((ext_vector_type(2))) float f2v;

// async global->LDS, 16B per lane; LDS dest is wave-uniform base + lane*16
#define GLOAD_LDS16(g, l)                                                      \
    __builtin_amdgcn_global_load_lds(                                          \
        (const __attribute__((address_space(1))) void*)(g),                    \
        (__attribute__((address_space(3))) void*)(l), 16, 0, 0)

__device__ __forceinline__ unsigned short f2bf(float f) {
    unsigned u = __builtin_bit_cast(unsigned, f);
    u += 0x7FFFu + ((u >> 16) & 1u);   // RNE
    return (unsigned short)(u >> 16);
}
__device__ __forceinline__ float lo_bf(unsigned u) {
    return __builtin_bit_cast(float, u << 16);
}
__device__ __forceinline__ float hi_bf(unsigned u) {
    return __builtin_bit_cast(float, u & 0xFFFF0000u);
}
// {lo,hi} pair for packed-add accumulation (v_pk_add_f32 eligible)
__device__ __forceinline__ f2v bfpair(unsigned u) {
    return f2v{__builtin_bit_cast(float, u << 16),
               __builtin_bit_cast(float, u & 0xFFFF0000u)};
}
__device__ __forceinline__ short8 cvt8(float4 lo, float4 hi) {
    return short8{(short)f2bf(lo.x), (short)f2bf(lo.y), (short)f2bf(lo.z), (short)f2bf(lo.w),
                  (short)f2bf(hi.x), (short)f2bf(hi.y), (short)f2bf(hi.z), (short)f2bf(hi.w)};
}
__device__ __forceinline__ unsigned pack_bf2(float a, float b) {
    return (unsigned)f2bf(a) | ((unsigned)f2bf(b) << 16);
}

// counted vmcnt wait (template-dispatched literal; asm needs an immediate)
template <int N>
__device__ __forceinline__ void waitvm() {
    if constexpr (N == 0) asm volatile("s_waitcnt vmcnt(0)" ::: "memory");
    else if constexpr (N == 3) asm volatile("s_waitcnt vmcnt(3)" ::: "memory");
    else if constexpr (N == 6) asm volatile("s_waitcnt vmcnt(6)" ::: "memory");
    else static_assert(N == 0 || N == 3 || N == 6, "add literal");
}
#define LGKM0() asm volatile("s_waitcnt lgkmcnt(0)" ::: "memory")
#define BAR() __builtin_amdgcn_s_barrier()
#define SCHED0() __builtin_amdgcn_sched_barrier(0)

// ---------------- partition: edges -> per-bucket staging ----------------
__global__ __launch_bounds__(256) void partition_kernel(
    const int* __restrict__ src, const int* __restrict__ dst,
    unsigned* __restrict__ staging, int* __restrict__ gcur,
    unsigned long long* __restrict__ ovbuf, int* __restrict__ ovcnt) {
    __shared__ unsigned buf[NBUK][LSLOT];
    __shared__ int cnt[NBUK];
    int tid = threadIdx.x;
    for (int b = tid; b < NBUK; b += 256) cnt[b] = 0;
    __syncthreads();
    constexpr int PER = (((N_EDGES + NBLK_A - 1) / NBLK_A) + 3) & ~3;   // 3128
    int e0 = blockIdx.x * PER;
    int e1 = min(e0 + PER, N_EDGES);

    auto body = [&](int d, int s) {
        int b = d >> BK_SHIFT;
        unsigned rec = (unsigned)s | ((unsigned)(d & 1023) << 17);
        int slot = atomicAdd(&cnt[b], 1);
        if (slot < LSLOT) {
            buf[b][slot] = rec;
        } else {  // rare LDS overflow: spill (src,dst) to global list
            int op = atomicAdd(ovcnt, 1);
            if (op < OV_CAP)
                ovbuf[op] = ((unsigned long long)(unsigned)d << 32) | (unsigned)s;
        }
    };
    auto drain = [&](void) {
        for (int b = tid; b < NBUK; b += 256) {
            int c = min(cnt[b], LSLOT);
            int full = c & ~15;
            if (full > 0) {
                int pos = atomicAdd(&gcur[b], full);
                if (pos + full <= SCAP) {
                    unsigned* dp = &staging[(size_t)b * SCAP + pos];
                    for (int i = 0; i < full; ++i) dp[i] = buf[b][i];
                }
                for (int i = 0; i < c - full; ++i) buf[b][i] = buf[b][full + i];
            }
            cnt[b] = c - full;
        }
    };

    int base = e0;
    for (; base + 1024 <= e1; base += 1024) {
        int e = base + tid * 4;
        int4 dv = *(const int4*)(dst + e);   // 16B vectorized edge loads
        int4 sv = *(const int4*)(src + e);
        body(dv.x, sv.x);
        body(dv.y, sv.y);
        body(dv.z, sv.z);
        body(dv.w, sv.w);
        __syncthreads();
        drain();
        __syncthreads();
    }
    for (int e = base + tid; e < e1; e += 256) body(dst[e], src[e]);
    __syncthreads();
    drain();
    __syncthreads();
    for (int b = tid; b < NBUK; b += 256) {
        int c = cnt[b];
        if (c > 0) {
            int pos = atomicAdd(&gcur[b], c);
            if (pos + c <= SCAP)
                for (int i = 0; i < c; ++i) staging[(size_t)b * SCAP + pos + i] = buf[b][i];
        }
    }
}

// ---------------- bucket_scan: 98 bucket totals -> bucket_base (1 block) ----------------
__global__ __launch_bounds__(128) void bucket_scan_kernel(
    const int* __restrict__ gcur, const unsigned long long* __restrict__ ovbuf,
    const int* __restrict__ ovcnt, int* __restrict__ bucket_base,
    int* __restrict__ row_ptr) {
    __shared__ int ovc[128];
    __shared__ int sc[128];
    int tid = threadIdx.x;
    ovc[tid] = 0;
    int tot = (tid < NBUK) ? min(gcur[tid], SCAP) : 0;
    __syncthreads();
    int oc = *ovcnt;
    if (oc > OV_CAP) oc = OV_CAP;
    for (int k = tid; k < oc; k += 128)
        atomicAdd(&ovc[(int)(ovbuf[k] >> 32) >> BK_SHIFT], 1);
    __syncthreads();
    int v = tot + ovc[tid];
    sc[tid] = v;
    __syncthreads();
    for (int d = 1; d < 128; d <<= 1) {
        int u = (tid >= d) ? sc[tid - d] : 0;
        __syncthreads();
        sc[tid] += u;
        __syncthreads();
    }
    if (tid < NBUK) bucket_base[tid] = sc[tid] - v;   // exclusive
    if (tid == NBUK - 1) {
        bucket_base[NBUK] = sc[tid];
        row_ptr[N_NODES] = sc[tid];
    }
}

// ---------------- deg_hist_row: per-bucket histogram + LDS scan -> row_ptr, dinv ----------------
__global__ __launch_bounds__(256) void deg_hist_row_kernel(
    const unsigned* __restrict__ staging, const int* __restrict__ gcur,
    const unsigned long long* __restrict__ ovbuf, const int* __restrict__ ovcnt,
    const int* __restrict__ bucket_base, int* __restrict__ row_ptr,
    float* __restrict__ dinv) {
    int b = blockIdx.x;
    __shared__ int hist[1024];
    __shared__ int psum[256];
    int tid = threadIdx.x;
    for (int i = tid; i < 1024; i += 256) hist[i] = 0;
    __syncthreads();
    int n = gcur[b];
    if (n > SCAP) n = SCAP;
    const unsigned* sp = &staging[(size_t)b * SCAP];
    int i = tid * 4;
    for (; i + 4 <= n; i += 1024) {
        uint4 r = *(const uint4*)(sp + i);
        atomicAdd(&hist[r.x >> 17], 1);
        atomicAdd(&hist[r.y >> 17], 1);
        atomicAdd(&hist[r.z >> 17], 1);
        atomicAdd(&hist[r.w >> 17], 1);
    }
    int tail0 = n & ~3;
    if (tid < (n - tail0)) atomicAdd(&hist[sp[tail0 + tid] >> 17], 1);
    int oc = *ovcnt;
    if (oc > OV_CAP) oc = OV_CAP;
    for (int k = tid; k < oc; k += 256) {
        int d = (int)(ovbuf[k] >> 32);
        if ((d >> BK_SHIFT) == b) atomicAdd(&hist[d & 1023], 1);
    }
    __syncthreads();
    int i4 = tid * 4;
    int s0 = hist[i4], s1 = hist[i4 + 1], s2 = hist[i4 + 2], s3 = hist[i4 + 3];
    int ms = s0 + s1 + s2 + s3;
    psum[tid] = ms;
    __syncthreads();
    for (int d = 1; d < 256; d <<= 1) {
        int u = (tid >= d) ? psum[tid - d] : 0;
        __syncthreads();
        psum[tid] += u;
        __syncthreads();
    }
    int ex = psum[tid] - ms + bucket_base[b];
    int nd = (b << BK_SHIFT) + i4;
    if (nd < N_NODES) {
        row_ptr[nd]     = ex;
        row_ptr[nd + 1] = ex + s0;
        row_ptr[nd + 2] = ex + s0 + s1;
        row_ptr[nd + 3] = ex + s0 + s1 + s2;
        dinv[nd]     = rsqrtf((float)(s0 + 1));
        dinv[nd + 1] = rsqrtf((float)(s1 + 1));
        dinv[nd + 2] = rsqrtf((float)(s2 + 1));
        dinv[nd + 3] = rsqrtf((float)(s3 + 1));
    }
}

// ---------------- fill: slice-owned node ranges + LDS cursors ----------------
__global__ __launch_bounds__(256) void fill_kernel(
    const unsigned* __restrict__ staging, const int* __restrict__ gcur,
    const int* __restrict__ row_ptr, int* __restrict__ csr_src,
    const unsigned long long* __restrict__ ovbuf, const int* __restrict__ ovcnt) {
    int b = blockIdx.x / FILL_SPLIT;
    int slice = blockIdx.x - b * FILL_SPLIT;
    int dl0 = slice * NPS;
    int node0 = (b << BK_SHIFT) + dl0;
    __shared__ int lcur[NPS];
    int tid = threadIdx.x;
    if (tid < NPS) {
        int nd = node0 + tid;
        lcur[tid] = (nd < N_NODES) ? row_ptr[nd] : 0;
    }
    __syncthreads();

    int n = gcur[b];
    if (n > SCAP) n = SCAP;
    const unsigned* sp = &staging[(size_t)b * SCAP];

    auto process = [&](unsigned rec) {
        int dl = (int)(rec >> 17) - dl0;
        if ((unsigned)dl < (unsigned)NPS) {
            int pos = atomicAdd(&lcur[dl], 1);
            csr_src[pos] = (int)(rec & 0x1FFFFu);
        }
    };

    int i = tid * 4;
    for (; i + 4 <= n; i += 1024) {
        uint4 r = *(const uint4*)(sp + i);
        process(r.x);
        process(r.y);
        process(r.z);
        process(r.w);
    }
    int tail0 = n & ~3;
    if (tid < (n - tail0)) process(sp[tail0 + tid]);

    int oc = *ovcnt;
    if (oc > OV_CAP) oc = OV_CAP;
    for (int k = tid; k < oc; k += 256) {
        unsigned long long r = ovbuf[k];
        int d = (int)(r >> 32);
        int dl = d - node0;
        if ((d >> BK_SHIFT) == b && (unsigned)dl < (unsigned)NPS) {
            int pos = atomicAdd(&lcur[dl], 1);
            csr_src[pos] = (int)(r & 0xffffffffu);
        }
    }
}

// ---------------- W transpose+convert: Wt[n][k] bf16 ----------------

__global__ void transpose_w_kernel(const float* __restrict__ W1, const float* __restrict__ W2,
                                   unsigned short* __restrict__ Wt1,
                                   unsigned short* __restrict__ Wt2) {
    int g = blockIdx.x * 256 + threadIdx.x;
    if (g < F_HID * F_IN) {               // Wt1: [128][512]
        int n = g >> 9, k = g & 511;
        Wt1[g] = f2bf(W1[k * F_HID + n]);
    } else {
        int h = g - F_HID * F_IN;         // Wt2: [64][128]
        if (h < F_OUT * F_HID) {
            int n = h >> 7, k = h & 127;
            Wt2[h] = f2bf(W2[k * F_OUT + n]);
        }
    }
}

// ---------------- LDS-staged MFMA GEMM, counted-vmcnt pipeline (T3+T4) ----------------
// R13: nbase param — dup launch uses grid 2*nbase with bid folded mod nbase
// (idempotent duplicate dispatch for measurement; dur/2 = true kernel cost).

template <int BN, int K, bool A_BF16>
__global__ __launch_bounds__(256, 3) void gemm_lds_kernel(
    const void* __restrict__ Araw, const unsigned short* __restrict__ Wt,
    const float* __restrict__ dinv, unsigned short* __restrict__ out, int N, int nbase) {
    constexpr int NCT = BN / 16;
    constexpr int AE = A_BF16 ? 2 : 4;
    constexpr int SLOTS_A = (32 * AE) / 16;
    constexpr int MA = SLOTS_A - 1;
    constexpr int ABYTES = 128 * 32 * AE;
    constexpr int BBYTES = BN * 32 * 2;
    constexpr int NT = K / 32;
    constexpr int SL = (128 * SLOTS_A + BN * 4) / 256;

    __shared__ __align__(128) char Abuf[2][ABYTES];
    __shared__ __align__(128) char Bbuf[2][BBYTES];

    const char* Ab = (const char*)Araw;
    const char* Bb = (const char*)Wt;
    int tid = threadIdx.x;
    int lane = tid & 63;
    int wv = tid >> 6;
    int bid = blockIdx.x;
    if (bid >= nbase) bid -= nbase;
    int row0 = bid * 128;
    int l15 = lane & 15;
    int q = lane >> 4;

    float4v acc[2][NCT] = {};

    auto stage = [&](int buf, int k0) {
        constexpr int CA = 128 * SLOTS_A;
#pragma unroll
        for (int i = 0; i < CA / 256; ++i) {
            int c = i * 256 + tid;
            int cw = i * 256 + (tid & ~63);
            int row = c / SLOTS_A;
            int s = c & MA;
            int g = s ^ (row & MA);
            int rg = row0 + row;
            if (rg >= N) rg = N - 1;
            GLOAD_LDS16(Ab + ((size_t)rg * K + k0) * AE + g * 16,
                        &Abuf[buf][cw * 16]);
        }
        constexpr int CB = BN * 4;
#pragma unroll
        for (int i = 0; i < CB / 256; ++i) {
            int c = i * 256 + tid;
            int cw = i * 256 + (tid & ~63);
            int col = c >> 2;
            int s = c & 3;
            int g = s ^ (col & 3);
            GLOAD_LDS16(Bb + ((size_t)col * K + k0) * 2 + g * 16,
                        &Bbuf[buf][cw * 16]);
        }
    };

    auto compute = [&](int buf) {
        const char* Ac = Abuf[buf];
        const char* Bc = Bbuf[buf];
        int lr0 = wv * 32 + l15;
        int lr1 = lr0 + 16;
        short8 a0, a1;
        if constexpr (A_BF16) {
            int s0 = q ^ (lr0 & 3);
            int s1 = q ^ (lr1 & 3);
            a0 = *(const short8*)(Ac + lr0 * 64 + s0 * 16);
            a1 = *(const short8*)(Ac + lr1 * 64 + s1 * 16);
        } else {
            int r7a = lr0 & 7, r7b = lr1 & 7;
            float4 f0 = *(const float4*)(Ac + lr0 * 128 + ((2 * q) ^ r7a) * 16);
            float4 f1 = *(const float4*)(Ac + lr0 * 128 + ((2 * q + 1) ^ r7a) * 16);
            float4 f2 = *(const float4*)(Ac + lr1 * 128 + ((2 * q) ^ r7b) * 16);
            float4 f3 = *(const float4*)(Ac + lr1 * 128 + ((2 * q + 1) ^ r7b) * 16);
            a0 = cvt8(f0, f1);
            a1 = cvt8(f2, f3);
        }
#pragma unroll
        for (int ct = 0; ct < NCT; ++ct) {
            int col = ct * 16 + l15;
            int sb = q ^ (col & 3);
            short8 b = *(const short8*)(Bc + col * 64 + sb * 16);
            acc[0][ct] = __builtin_amdgcn_mfma_f32_16x16x32_bf16(a0, b, acc[0][ct], 0, 0, 0);
            acc[1][ct] = __builtin_amdgcn_mfma_f32_16x16x32_bf16(a1, b, acc[1][ct], 0, 0, 0);
        }
    };

    stage(0, 0);
    stage(1, 32);
#pragma unroll 1
    for (int t = 0; t < NT - 2; ++t) {
        waitvm<SL>();
        BAR();
        SCHED0();
        compute(t & 1);
        LGKM0();
        BAR();
        SCHED0();
        stage(t & 1, (t + 2) * 32);
    }
    waitvm<SL>();
    BAR();
    SCHED0();
    compute((NT - 2) & 1);
    waitvm<0>();
    BAR();
    SCHED0();
    compute((NT - 1) & 1);

#pragma unroll
    for (int rt = 0; rt < 2; ++rt) {
#pragma unroll
        for (int reg = 0; reg < 4; ++reg) {
            int row = row0 + wv * 32 + rt * 16 + q * 4 + reg;
            if (row < N) {
                float sc = dinv[row];
#pragma unroll
                for (int ct = 0; ct < NCT; ++ct) {
                    out[(size_t)row * BN + ct * 16 + l15] = f2bf(acc[rt][ct][reg] * sc);
                }
            }
        }
    }
}

// ---------------- aggregation v4 (R12 structure) + nbase dup support ----------------

__global__ __launch_bounds__(256) void agg1_kernel(
    const uint4* __restrict__ g1v, const int* __restrict__ row_ptr,
    const int* __restrict__ csr_src, const float* __restrict__ dinv,
    const float4* __restrict__ b1v, uint4* __restrict__ h1v, int nbase) {
    int tid = threadIdx.x;
    int wv = tid >> 6;
    int lane = tid & 63;
    int qt = lane >> 4;
    int ql = lane & 15;
    int bid = blockIdx.x;
    if (bid >= nbase) bid -= nbase;
    int node = bid * 16 + wv * 4 + qt;
    uint4 u = g1v[(size_t)node * 16 + ql];
    f2v A0 = bfpair(u.x), A1 = bfpair(u.y), A2 = bfpair(u.z), A3 = bfpair(u.w);
    int e = row_ptr[node], end = row_ptr[node + 1];
#define GA1(j) g1v[(size_t)(j) * 16 + ql]
#define ACCV(v)                                                                \
    do { A0 += bfpair((v).x); A1 += bfpair((v).y);                             \
         A2 += bfpair((v).z); A3 += bfpair((v).w); } while (0)
    if (e + 8 <= end) {
        int j0 = csr_src[e], j1 = csr_src[e + 1], j2 = csr_src[e + 2], j3 = csr_src[e + 3];
        int j4 = csr_src[e + 4], j5 = csr_src[e + 5], j6 = csr_src[e + 6], j7 = csr_src[e + 7];
        uint4 v0 = GA1(j0), v1 = GA1(j1), v2 = GA1(j2), v3 = GA1(j3);
        uint4 v4 = GA1(j4), v5 = GA1(j5), v6 = GA1(j6), v7 = GA1(j7);
        e += 8;
        for (; e + 8 <= end; e += 8) {
            int k0 = csr_src[e], k1 = csr_src[e + 1], k2 = csr_src[e + 2], k3 = csr_src[e + 3];
            int k4 = csr_src[e + 4], k5 = csr_src[e + 5], k6 = csr_src[e + 6], k7 = csr_src[e + 7];
            ACCV(v0); ACCV(v1); ACCV(v2); ACCV(v3);
            ACCV(v4); ACCV(v5); ACCV(v6); ACCV(v7);
            v0 = GA1(k0); v1 = GA1(k1); v2 = GA1(k2); v3 = GA1(k3);
            v4 = GA1(k4); v5 = GA1(k5); v6 = GA1(k6); v7 = GA1(k7);
        }
        ACCV(v0); ACCV(v1); ACCV(v2); ACCV(v3);
        ACCV(v4); ACCV(v5); ACCV(v6); ACCV(v7);
    }
    for (; e < end; ++e) {
        uint4 v = GA1(csr_src[e]);
        ACCV(v);
    }
#undef ACCV
#undef GA1
    float d = dinv[node];
    float4 ba = b1v[2 * ql], bb = b1v[2 * ql + 1];
    float r0 = fmaxf(d * A0.x + ba.x, 0.0f), r1 = fmaxf(d * A0.y + ba.y, 0.0f);
    float r2 = fmaxf(d * A1.x + ba.z, 0.0f), r3 = fmaxf(d * A1.y + ba.w, 0.0f);
    float r4 = fmaxf(d * A2.x + bb.x, 0.0f), r5 = fmaxf(d * A2.y + bb.y, 0.0f);
    float r6 = fmaxf(d * A3.x + bb.z, 0.0f), r7 = fmaxf(d * A3.y + bb.w, 0.0f);
    h1v[(size_t)node * 16 + ql] =
        uint4{pack_bf2(r0, r1), pack_bf2(r2, r3), pack_bf2(r4, r5), pack_bf2(r6, r7)};
}

__global__ __launch_bounds__(256) void agg2_lsm_kernel(
    const uint2* __restrict__ g2v, const int* __restrict__ row_ptr,
    const int* __restrict__ csr_src, const float* __restrict__ dinv,
    const float4* __restrict__ b2v, float4* __restrict__ outv) {
    int tid = threadIdx.x;
    int wv = tid >> 6;
    int lane = tid & 63;
    int qt = lane >> 4;
    int ql = lane & 15;
    int node = blockIdx.x * 16 + wv * 4 + qt;
    uint2 u = g2v[(size_t)node * 16 + ql];
    f2v A0 = bfpair(u.x), A1 = bfpair(u.y);
    int e = row_ptr[node], end = row_ptr[node + 1];
#define GA2(j) g2v[(size_t)(j) * 16 + ql]
#define ACCV(v) do { A0 += bfpair((v).x); A1 += bfpair((v).y); } while (0)
    if (e + 8 <= end) {
        int j0 = csr_src[e], j1 = csr_src[e + 1], j2 = csr_src[e + 2], j3 = csr_src[e + 3];
        int j4 = csr_src[e + 4], j5 = csr_src[e + 5], j6 = csr_src[e + 6], j7 = csr_src[e + 7];
        uint2 v0 = GA2(j0), v1 = GA2(j1), v2 = GA2(j2), v3 = GA2(j3);
        uint2 v4 = GA2(j4), v5 = GA2(j5), v6 = GA2(j6), v7 = GA2(j7);
        e += 8;
        for (; e + 8 <= end; e += 8) {
            int k0 = csr_src[e], k1 = csr_src[e + 1], k2 = csr_src[e + 2], k3 = csr_src[e + 3];
            int k4 = csr_src[e + 4], k5 = csr_src[e + 5], k6 = csr_src[e + 6], k7 = csr_src[e + 7];
            ACCV(v0); ACCV(v1); ACCV(v2); ACCV(v3);
            ACCV(v4); ACCV(v5); ACCV(v6); ACCV(v7);
            v0 = GA2(k0); v1 = GA2(k1); v2 = GA2(k2); v3 = GA2(k3);
            v4 = GA2(k4); v5 = GA2(k5); v6 = GA2(k6); v7 = GA2(k7);
        }
        ACCV(v0); ACCV(v1); ACCV(v2); ACCV(v3);
        ACCV(v4); ACCV(v5); ACCV(v6); ACCV(v7);
    }
    for (; e < end; ++e) {
        uint2 v = GA2(csr_src[e]);
        ACCV(v);
    }
#undef ACCV
#undef GA2
    float d = dinv[node];
    float4 b = b2v[ql];
    float v0 = d * A0.x + b.x;
    float v1 = d * A0.y + b.y;
    float v2 = d * A1.x + b.z;
    float v3 = d * A1.y + b.w;
    float m = fmaxf(fmaxf(v0, v1), fmaxf(v2, v3));
#pragma unroll
    for (int o = 8; o > 0; o >>= 1) m = fmaxf(m, __shfl_xor(m, o, 64));
    float s = __expf(v0 - m) + __expf(v1 - m) + __expf(v2 - m) + __expf(v3 - m);
#pragma unroll
    for (int o = 8; o > 0; o >>= 1) s += __shfl_xor(s, o, 64);
    float ls = m + __logf(s);
    outv[(size_t)node * 16 + ql] = float4{v0 - ls, v1 - ls, v2 - ls, v3 - ls};
}

// ---------------- launch ----------------

extern "C" void kernel_launch(void* const* d_in, const int* in_sizes, int n_in,
                              void* d_out, int out_size, void* d_ws, size_t ws_size,
                              hipStream_t stream) {
    const float* x  = (const float*)d_in[0];
    const int* eidx = (const int*)d_in[1];
    const float* W1 = (const float*)d_in[2];
    const float* b1 = (const float*)d_in[3];
    const float* W2 = (const float*)d_in[4];
    const float* b2 = (const float*)d_in[5];
    float* out = (float*)d_out;
    const int* src = eidx;
    const int* dst = eidx + N_EDGES;

    char* base = (char*)d_ws;
    size_t off = 0;
    auto alloc = [&](size_t bytes) -> void* {
        void* p = base + off;
        off += (bytes + 255) & ~(size_t)255;
        return p;
    };
    int* zbase    = (int*)alloc((size_t)(NBUK + 64) * 4);
    int* gcur     = zbase;
    int* ovcnt    = zbase + NBUK;
    int* bucket_base = (int*)alloc((size_t)(NBUK + 1) * 4);
    int* row_ptr  = (int*)alloc((size_t)(N_NODES + 1) * 4);
    float* dinv   = (float*)alloc((size_t)N_NODES * 4);
    unsigned* staging = (unsigned*)alloc((size_t)NBUK * SCAP * 4);   // 9.6 MB
    unsigned long long* ovbuf = (unsigned long long*)alloc((size_t)OV_CAP * 8);
    int* csr_src  = (int*)alloc((size_t)N_EDGES * 4);
    unsigned short* Wt1 = (unsigned short*)alloc((size_t)F_HID * F_IN * 2);
    unsigned short* Wt2 = (unsigned short*)alloc((size_t)F_OUT * F_HID * 2);
    unsigned short* g1  = (unsigned short*)alloc((size_t)N_NODES * F_HID * 2);
    unsigned short* h1  = (unsigned short*)alloc((size_t)N_NODES * F_HID * 2);
    unsigned short* g2  = g1;  // g1 dead after agg1

    hipMemsetAsync(zbase, 0, (size_t)(NBUK + 64) * 4, stream);
    partition_kernel<<<NBLK_A, 256, 0, stream>>>(src, dst, staging, gcur, ovbuf, ovcnt);
    bucket_scan_kernel<<<1, 128, 0, stream>>>(gcur, ovbuf, ovcnt, bucket_base, row_ptr);
    deg_hist_row_kernel<<<NBUK, 256, 0, stream>>>(staging, gcur, ovbuf, ovcnt,
                                                  bucket_base, row_ptr, dinv);
    fill_kernel<<<NBUK * FILL_SPLIT, 256, 0, stream>>>(staging, gcur, row_ptr, csr_src,
                                                       ovbuf, ovcnt);
    transpose_w_kernel<<<(F_HID * F_IN + F_OUT * F_HID + 255) / 256, 256, 0, stream>>>(
        W1, W2, Wt1, Wt2);

    int gblocks = (N_NODES + 127) / 128;  // 782
    int ablocks = N_NODES / 16;           // 6250
    gemm_lds_kernel<F_HID, F_IN, false><<<gblocks, 256, 0, stream>>>(
        (const void*)x, Wt1, dinv, g1, N_NODES, gblocks);
    // R13 MEASUREMENT: idempotent x2-grid duplicate -> dispatch dur = 2*gemm1;
    // appears in top-5 with counters if gemm1 >= ~61us. Remove next round.
    gemm_lds_kernel<F_HID, F_IN, false><<<2 * gblocks, 256, 0, stream>>>(
        (const void*)x, Wt1, dinv, g1, N_NODES, gblocks);
    agg1_kernel<<<ablocks, 256, 0, stream>>>(
        (const uint4*)g1, row_ptr, csr_src, dinv, (const float4*)b1, (uint4*)h1, ablocks);
    // R13 MEASUREMENT: same for agg1.
    agg1_kernel<<<2 * ablocks, 256, 0, stream>>>(
        (const uint4*)g1, row_ptr, csr_src, dinv, (const float4*)b1, (uint4*)h1, ablocks);

    gemm_lds_kernel<F_OUT, F_HID, true><<<gblocks, 256, 0, stream>>>(
        (const void*)h1, Wt2, dinv, g2, N_NODES, gblocks);
    agg2_lsm_kernel<<<N_NODES / 16, 256, 0, stream>>>(
        (const uint2*)g2, row_ptr, csr_src, dinv, (const float4*)b2, (float4*)out);
}

// Round 11
// 493.868 us; speedup vs baseline: 1.4128x; 1.4128x over previous
//
#include <hip/hip_runtime.h>
#include <cmath>

#define N_NODES 100000
#define N_EDGES 1600000
#define F_IN 512
#define F_HID 128
#define F_OUT 64

// ---- bucketed CSR-build params ----
#define BK_SHIFT 10                        // 1024 nodes per bucket
#define NBUK ((N_NODES + 1023) >> 10)      // 98 buckets
#define NBLK_A 512                         // partition blocks (2/CU)
#define PCAP 64                            // words per (block,bucket) segment; load ~Poisson(32), +5.6 sigma
#define SEGW (NBUK * PCAP)                 // 6272 words per block segment
#define FILL_SPLIT 8                       // slice-blocks per bucket, disjoint node ranges
#define NPS (1024 / FILL_SPLIT)            // 128 nodes per slice
#define OV_CAP 4096                        // global overflow records

typedef __attribute__((ext_vector_type(8))) short short8;
typedef __attribute__((ext_vector_type(4))) float float4v;
typedef __attribute__((ext_vector_type(2))) float f2v;

// async global->LDS, 16B per lane; LDS dest is wave-uniform base + lane*16
#define GLOAD_LDS16(g, l)                                                      \
    __builtin_amdgcn_global_load_lds(                                          \
        (const __attribute__((address_space(1))) void*)(g),                    \
        (__attribute__((address_space(3))) void*)(l), 16, 0, 0)

__device__ __forceinline__ unsigned short f2bf(float f) {
    unsigned u = __builtin_bit_cast(unsigned, f);
    u += 0x7FFFu + ((u >> 16) & 1u);   // RNE
    return (unsigned short)(u >> 16);
}
__device__ __forceinline__ float lo_bf(unsigned u) {
    return __builtin_bit_cast(float, u << 16);
}
__device__ __forceinline__ float hi_bf(unsigned u) {
    return __builtin_bit_cast(float, u & 0xFFFF0000u);
}
// {lo,hi} pair for packed-add accumulation (v_pk_add_f32 eligible)
__device__ __forceinline__ f2v bfpair(unsigned u) {
    return f2v{__builtin_bit_cast(float, u << 16),
               __builtin_bit_cast(float, u & 0xFFFF0000u)};
}
__device__ __forceinline__ short8 cvt8(float4 lo, float4 hi) {
    return short8{(short)f2bf(lo.x), (short)f2bf(lo.y), (short)f2bf(lo.z), (short)f2bf(lo.w),
                  (short)f2bf(hi.x), (short)f2bf(hi.y), (short)f2bf(hi.z), (short)f2bf(hi.w)};
}
__device__ __forceinline__ unsigned pack_bf2(float a, float b) {
    return (unsigned)f2bf(a) | ((unsigned)f2bf(b) << 16);
}

// counted vmcnt wait (template-dispatched literal; asm needs an immediate)
template <int N>
__device__ __forceinline__ void waitvm() {
    if constexpr (N == 0) asm volatile("s_waitcnt vmcnt(0)" ::: "memory");
    else if constexpr (N == 3) asm volatile("s_waitcnt vmcnt(3)" ::: "memory");
    else if constexpr (N == 6) asm volatile("s_waitcnt vmcnt(6)" ::: "memory");
    else static_assert(N == 0 || N == 3 || N == 6, "add literal");
}
#define LGKM0() asm volatile("s_waitcnt lgkmcnt(0)" ::: "memory")
#define BAR() __builtin_amdgcn_s_barrier()
#define SCHED0() __builtin_amdgcn_sched_barrier(0)

// ---------------- partition v3: per-block staging segments, ZERO global atomics ----------------
// R14 (from R13 measurement: gemm1+agg1 only ~97us -> CSR build is ~350us).
// Old partition: per-tile drains with global atomicAdd(&gcur[b]) on 98 addresses
// shared by 512 blocks across 8 XCDs (cross-XCD line ping-pong, the R9 disease)
// + 2 barriers/tile + serial scalar copies. Now: each block owns a private
// staging segment staging[blk][98][64]; edges accumulate in LDS only (1 atomic
// + 1 store per edge), ONE bulk coalesced 25KB flush at the end, counts to
// cnt_t[b][blk] (bucket-major -> coalesced consumers). No gcur. No drains.
__global__ __launch_bounds__(256) void partition_kernel(
    const int* __restrict__ src, const int* __restrict__ dst,
    unsigned* __restrict__ staging, int* __restrict__ cnt_t,
    unsigned long long* __restrict__ ovbuf, int* __restrict__ ovcnt) {
    __shared__ __align__(16) unsigned buf[NBUK][PCAP];   // 25088 B
    __shared__ int cnt[NBUK];
    int tid = threadIdx.x;
    for (int b = tid; b < NBUK; b += 256) cnt[b] = 0;
    __syncthreads();
    constexpr int PER = (((N_EDGES + NBLK_A - 1) / NBLK_A) + 3) & ~3;   // 3128
    int e0 = blockIdx.x * PER;
    int e1 = min(e0 + PER, N_EDGES);

    auto body = [&](int d, int s) {
        int b = d >> BK_SHIFT;
        unsigned rec = (unsigned)s | ((unsigned)(d & 1023) << 17);
        int slot = atomicAdd(&cnt[b], 1);
        if (slot < PCAP) {
            buf[b][slot] = rec;
        } else {  // ~5.6-sigma rare: spill (dst,src) to global overflow list
            int op = atomicAdd(ovcnt, 1);
            if (op < OV_CAP)
                ovbuf[op] = ((unsigned long long)(unsigned)d << 32) | (unsigned)s;
        }
    };

    int base = e0;
    for (; base + 1024 <= e1; base += 1024) {
        int e = base + tid * 4;
        int4 dv = *(const int4*)(dst + e);   // 16B vectorized edge loads
        int4 sv = *(const int4*)(src + e);
        body(dv.x, sv.x);
        body(dv.y, sv.y);
        body(dv.z, sv.z);
        body(dv.w, sv.w);
    }
    for (int e = base + tid; e < e1; e += 256) body(dst[e], src[e]);
    __syncthreads();
    // bulk flush: whole LDS buffer (incl. unused slots; readers use cnt) as uint4
    const uint4* lb = (const uint4*)buf;
    uint4* dp = (uint4*)(staging + (size_t)blockIdx.x * SEGW);
    for (int i = tid; i < SEGW / 4; i += 256) dp[i] = lb[i];
    for (int b = tid; b < NBUK; b += 256)
        cnt_t[(size_t)b * NBLK_A + blockIdx.x] = min(cnt[b], PCAP);
}

// ---------------- bucket_scan: bucket totals from cnt_t rows -> bucket_base (1 block) ----------------
__global__ __launch_bounds__(128) void bucket_scan_kernel(
    const int* __restrict__ cnt_t, const unsigned long long* __restrict__ ovbuf,
    const int* __restrict__ ovcnt, int* __restrict__ bucket_base,
    int* __restrict__ row_ptr) {
    __shared__ int ovc[128];
    __shared__ int sc[128];
    int tid = threadIdx.x;
    ovc[tid] = 0;
    int tot = 0;
    if (tid < NBUK) {   // bucket-major row is contiguous: 512 ints, int4 loads
        const int4* p = (const int4*)(cnt_t + (size_t)tid * NBLK_A);
        for (int i = 0; i < NBLK_A / 4; ++i) {
            int4 v = p[i];
            tot += v.x + v.y + v.z + v.w;
        }
    }
    __syncthreads();
    int oc = *ovcnt;
    if (oc > OV_CAP) oc = OV_CAP;
    for (int k = tid; k < oc; k += 128)
        atomicAdd(&ovc[(int)(ovbuf[k] >> 32) >> BK_SHIFT], 1);
    __syncthreads();
    int v = tot + ovc[tid];
    sc[tid] = v;
    __syncthreads();
    for (int d = 1; d < 128; d <<= 1) {
        int u = (tid >= d) ? sc[tid - d] : 0;
        __syncthreads();
        sc[tid] += u;
        __syncthreads();
    }
    if (tid < NBUK) bucket_base[tid] = sc[tid] - v;   // exclusive
    if (tid == NBUK - 1) {
        bucket_base[NBUK] = sc[tid];
        row_ptr[N_NODES] = sc[tid];
    }
}

// ---------------- deg_hist_row: histogram over 512 segments + LDS scan -> row_ptr, dinv ----------------
__global__ __launch_bounds__(256) void deg_hist_row_kernel(
    const unsigned* __restrict__ staging, const int* __restrict__ cnt_t,
    const unsigned long long* __restrict__ ovbuf, const int* __restrict__ ovcnt,
    const int* __restrict__ bucket_base, int* __restrict__ row_ptr,
    float* __restrict__ dinv) {
    int b = blockIdx.x;
    __shared__ int hist[1024];
    __shared__ int psum[256];
    __shared__ unsigned char cntl[NBLK_A];   // counts <= 64 fit uchar
    int tid = threadIdx.x;
    for (int i = tid; i < 1024; i += 256) hist[i] = 0;
    for (int blk = tid; blk < NBLK_A; blk += 256)
        cntl[blk] = (unsigned char)cnt_t[(size_t)b * NBLK_A + blk];   // coalesced 2KB
    __syncthreads();
    // scan segments: 16 uint4 quads per segment; qi -> (blk, quad)
    for (int qi = tid; qi < NBLK_A * (PCAP / 4); qi += 256) {
        int blk = qi >> 4;
        int s0 = (qi & 15) << 2;
        int c = cntl[blk];
        if (s0 < c) {
            uint4 r = *(const uint4*)(staging + (size_t)blk * SEGW + b * PCAP + s0);
            atomicAdd(&hist[r.x >> 17], 1);
            if (s0 + 1 < c) atomicAdd(&hist[r.y >> 17], 1);
            if (s0 + 2 < c) atomicAdd(&hist[r.z >> 17], 1);
            if (s0 + 3 < c) atomicAdd(&hist[r.w >> 17], 1);
        }
    }
    int oc = *ovcnt;
    if (oc > OV_CAP) oc = OV_CAP;
    for (int k = tid; k < oc; k += 256) {
        int d = (int)(ovbuf[k] >> 32);
        if ((d >> BK_SHIFT) == b) atomicAdd(&hist[d & 1023], 1);
    }
    __syncthreads();
    // exclusive scan of 1024 hist entries (thread owns 4)
    int i4 = tid * 4;
    int s0 = hist[i4], s1 = hist[i4 + 1], s2 = hist[i4 + 2], s3 = hist[i4 + 3];
    int ms = s0 + s1 + s2 + s3;
    psum[tid] = ms;
    __syncthreads();
    for (int d = 1; d < 256; d <<= 1) {
        int u = (tid >= d) ? psum[tid - d] : 0;
        __syncthreads();
        psum[tid] += u;
        __syncthreads();
    }
    int ex = psum[tid] - ms + bucket_base[b];
    int nd = (b << BK_SHIFT) + i4;
    if (nd < N_NODES) {   // N_NODES % 4 == 0 -> whole-group guard safe
        row_ptr[nd]     = ex;
        row_ptr[nd + 1] = ex + s0;
        row_ptr[nd + 2] = ex + s0 + s1;
        row_ptr[nd + 3] = ex + s0 + s1 + s2;
        dinv[nd]     = rsqrtf((float)(s0 + 1));
        dinv[nd + 1] = rsqrtf((float)(s1 + 1));
        dinv[nd + 2] = rsqrtf((float)(s2 + 1));
        dinv[nd + 3] = rsqrtf((float)(s3 + 1));
    }
}

// ---------------- fill: slice-owned node ranges + LDS cursors over 512 segments ----------------
__global__ __launch_bounds__(256) void fill_kernel(
    const unsigned* __restrict__ staging, const int* __restrict__ cnt_t,
    const int* __restrict__ row_ptr, int* __restrict__ csr_src,
    const unsigned long long* __restrict__ ovbuf, const int* __restrict__ ovcnt) {
    int b = blockIdx.x / FILL_SPLIT;
    int slice = blockIdx.x - b * FILL_SPLIT;
    int dl0 = slice * NPS;
    int node0 = (b << BK_SHIFT) + dl0;
    __shared__ int lcur[NPS];
    __shared__ unsigned char cntl[NBLK_A];
    int tid = threadIdx.x;
    if (tid < NPS) {
        int nd = node0 + tid;
        lcur[tid] = (nd < N_NODES) ? row_ptr[nd] : 0;
    }
    for (int blk = tid; blk < NBLK_A; blk += 256)
        cntl[blk] = (unsigned char)cnt_t[(size_t)b * NBLK_A + blk];
    __syncthreads();

    auto process = [&](unsigned rec) {
        int dl = (int)(rec >> 17) - dl0;
        if ((unsigned)dl < (unsigned)NPS) {
            int pos = atomicAdd(&lcur[dl], 1);
            csr_src[pos] = (int)(rec & 0x1FFFFu);
        }
    };

    for (int qi = tid; qi < NBLK_A * (PCAP / 4); qi += 256) {
        int blk = qi >> 4;
        int s0 = (qi & 15) << 2;
        int c = cntl[blk];
        if (s0 < c) {
            uint4 r = *(const uint4*)(staging + (size_t)blk * SEGW + b * PCAP + s0);
            process(r.x);
            if (s0 + 1 < c) process(r.y);
            if (s0 + 2 < c) process(r.z);
            if (s0 + 3 < c) process(r.w);
        }
    }

    int oc = *ovcnt;
    if (oc > OV_CAP) oc = OV_CAP;
    for (int k = tid; k < oc; k += 256) {
        unsigned long long r = ovbuf[k];
        int d = (int)(r >> 32);
        int dl = d - node0;
        if ((d >> BK_SHIFT) == b && (unsigned)dl < (unsigned)NPS) {
            int pos = atomicAdd(&lcur[dl], 1);
            csr_src[pos] = (int)(r & 0xffffffffu);
        }
    }
}

// ---------------- W transpose+convert: Wt[n][k] bf16 ----------------

__global__ void transpose_w_kernel(const float* __restrict__ W1, const float* __restrict__ W2,
                                   unsigned short* __restrict__ Wt1,
                                   unsigned short* __restrict__ Wt2) {
    int g = blockIdx.x * 256 + threadIdx.x;
    if (g < F_HID * F_IN) {               // Wt1: [128][512]
        int n = g >> 9, k = g & 511;
        Wt1[g] = f2bf(W1[k * F_HID + n]);
    } else {
        int h = g - F_HID * F_IN;         // Wt2: [64][128]
        if (h < F_OUT * F_HID) {
            int n = h >> 7, k = h & 127;
            Wt2[h] = f2bf(W2[k * F_OUT + n]);
        }
    }
}

// ---------------- LDS-staged MFMA GEMM, counted-vmcnt pipeline (T3+T4) ----------------

template <int BN, int K, bool A_BF16>
__global__ __launch_bounds__(256, 3) void gemm_lds_kernel(
    const void* __restrict__ Araw, const unsigned short* __restrict__ Wt,
    const float* __restrict__ dinv, unsigned short* __restrict__ out, int N) {
    constexpr int NCT = BN / 16;
    constexpr int AE = A_BF16 ? 2 : 4;
    constexpr int SLOTS_A = (32 * AE) / 16;
    constexpr int MA = SLOTS_A - 1;
    constexpr int ABYTES = 128 * 32 * AE;
    constexpr int BBYTES = BN * 32 * 2;
    constexpr int NT = K / 32;
    constexpr int SL = (128 * SLOTS_A + BN * 4) / 256;

    __shared__ __align__(128) char Abuf[2][ABYTES];
    __shared__ __align__(128) char Bbuf[2][BBYTES];

    const char* Ab = (const char*)Araw;
    const char* Bb = (const char*)Wt;
    int tid = threadIdx.x;
    int lane = tid & 63;
    int wv = tid >> 6;
    int row0 = blockIdx.x * 128;
    int l15 = lane & 15;
    int q = lane >> 4;

    float4v acc[2][NCT] = {};

    auto stage = [&](int buf, int k0) {
        constexpr int CA = 128 * SLOTS_A;
#pragma unroll
        for (int i = 0; i < CA / 256; ++i) {
            int c = i * 256 + tid;
            int cw = i * 256 + (tid & ~63);
            int row = c / SLOTS_A;
            int s = c & MA;
            int g = s ^ (row & MA);
            int rg = row0 + row;
            if (rg >= N) rg = N - 1;
            GLOAD_LDS16(Ab + ((size_t)rg * K + k0) * AE + g * 16,
                        &Abuf[buf][cw * 16]);
        }
        constexpr int CB = BN * 4;
#pragma unroll
        for (int i = 0; i < CB / 256; ++i) {
            int c = i * 256 + tid;
            int cw = i * 256 + (tid & ~63);
            int col = c >> 2;
            int s = c & 3;
            int g = s ^ (col & 3);
            GLOAD_LDS16(Bb + ((size_t)col * K + k0) * 2 + g * 16,
                        &Bbuf[buf][cw * 16]);
        }
    };

    auto compute = [&](int buf) {
        const char* Ac = Abuf[buf];
        const char* Bc = Bbuf[buf];
        int lr0 = wv * 32 + l15;
        int lr1 = lr0 + 16;
        short8 a0, a1;
        if constexpr (A_BF16) {
            int s0 = q ^ (lr0 & 3);
            int s1 = q ^ (lr1 & 3);
            a0 = *(const short8*)(Ac + lr0 * 64 + s0 * 16);
            a1 = *(const short8*)(Ac + lr1 * 64 + s1 * 16);
        } else {
            int r7a = lr0 & 7, r7b = lr1 & 7;
            float4 f0 = *(const float4*)(Ac + lr0 * 128 + ((2 * q) ^ r7a) * 16);
            float4 f1 = *(const float4*)(Ac + lr0 * 128 + ((2 * q + 1) ^ r7a) * 16);
            float4 f2 = *(const float4*)(Ac + lr1 * 128 + ((2 * q) ^ r7b) * 16);
            float4 f3 = *(const float4*)(Ac + lr1 * 128 + ((2 * q + 1) ^ r7b) * 16);
            a0 = cvt8(f0, f1);
            a1 = cvt8(f2, f3);
        }
#pragma unroll
        for (int ct = 0; ct < NCT; ++ct) {
            int col = ct * 16 + l15;
            int sb = q ^ (col & 3);
            short8 b = *(const short8*)(Bc + col * 64 + sb * 16);
            acc[0][ct] = __builtin_amdgcn_mfma_f32_16x16x32_bf16(a0, b, acc[0][ct], 0, 0, 0);
            acc[1][ct] = __builtin_amdgcn_mfma_f32_16x16x32_bf16(a1, b, acc[1][ct], 0, 0, 0);
        }
    };

    stage(0, 0);
    stage(1, 32);
#pragma unroll 1
    for (int t = 0; t < NT - 2; ++t) {
        waitvm<SL>();
        BAR();
        SCHED0();
        compute(t & 1);
        LGKM0();
        BAR();
        SCHED0();
        stage(t & 1, (t + 2) * 32);
    }
    waitvm<SL>();
    BAR();
    SCHED0();
    compute((NT - 2) & 1);
    waitvm<0>();
    BAR();
    SCHED0();
    compute((NT - 1) & 1);

#pragma unroll
    for (int rt = 0; rt < 2; ++rt) {
#pragma unroll
        for (int reg = 0; reg < 4; ++reg) {
            int row = row0 + wv * 32 + rt * 16 + q * 4 + reg;
            if (row < N) {
                float sc = dinv[row];
#pragma unroll
                for (int ct = 0; ct < NCT; ++ct) {
                    out[(size_t)row * BN + ct * 16 + l15] = f2bf(acc[rt][ct][reg] * sc);
                }
            }
        }
    }
}

// ---------------- aggregation v4: 4 nodes/wave, 2-batch pipeline, packed-pair accum ----------------

__global__ __launch_bounds__(256) void agg1_kernel(
    const uint4* __restrict__ g1v, const int* __restrict__ row_ptr,
    const int* __restrict__ csr_src, const float* __restrict__ dinv,
    const float4* __restrict__ b1v, uint4* __restrict__ h1v) {
    int tid = threadIdx.x;
    int wv = tid >> 6;
    int lane = tid & 63;
    int qt = lane >> 4;
    int ql = lane & 15;
    int node = blockIdx.x * 16 + wv * 4 + qt;
    uint4 u = g1v[(size_t)node * 16 + ql];
    f2v A0 = bfpair(u.x), A1 = bfpair(u.y), A2 = bfpair(u.z), A3 = bfpair(u.w);
    int e = row_ptr[node], end = row_ptr[node + 1];
#define GA1(j) g1v[(size_t)(j) * 16 + ql]
#define ACCV(v)                                                                \
    do { A0 += bfpair((v).x); A1 += bfpair((v).y);                             \
         A2 += bfpair((v).z); A3 += bfpair((v).w); } while (0)
    if (e + 8 <= end) {
        int j0 = csr_src[e], j1 = csr_src[e + 1], j2 = csr_src[e + 2], j3 = csr_src[e + 3];
        int j4 = csr_src[e + 4], j5 = csr_src[e + 5], j6 = csr_src[e + 6], j7 = csr_src[e + 7];
        uint4 v0 = GA1(j0), v1 = GA1(j1), v2 = GA1(j2), v3 = GA1(j3);
        uint4 v4 = GA1(j4), v5 = GA1(j5), v6 = GA1(j6), v7 = GA1(j7);
        e += 8;
        for (; e + 8 <= end; e += 8) {
            int k0 = csr_src[e], k1 = csr_src[e + 1], k2 = csr_src[e + 2], k3 = csr_src[e + 3];
            int k4 = csr_src[e + 4], k5 = csr_src[e + 5], k6 = csr_src[e + 6], k7 = csr_src[e + 7];
            ACCV(v0); ACCV(v1); ACCV(v2); ACCV(v3);
            ACCV(v4); ACCV(v5); ACCV(v6); ACCV(v7);
            v0 = GA1(k0); v1 = GA1(k1); v2 = GA1(k2); v3 = GA1(k3);
            v4 = GA1(k4); v5 = GA1(k5); v6 = GA1(k6); v7 = GA1(k7);
        }
        ACCV(v0); ACCV(v1); ACCV(v2); ACCV(v3);
        ACCV(v4); ACCV(v5); ACCV(v6); ACCV(v7);
    }
    for (; e < end; ++e) {
        uint4 v = GA1(csr_src[e]);
        ACCV(v);
    }
#undef ACCV
#undef GA1
    float d = dinv[node];
    float4 ba = b1v[2 * ql], bb = b1v[2 * ql + 1];
    float r0 = fmaxf(d * A0.x + ba.x, 0.0f), r1 = fmaxf(d * A0.y + ba.y, 0.0f);
    float r2 = fmaxf(d * A1.x + ba.z, 0.0f), r3 = fmaxf(d * A1.y + ba.w, 0.0f);
    float r4 = fmaxf(d * A2.x + bb.x, 0.0f), r5 = fmaxf(d * A2.y + bb.y, 0.0f);
    float r6 = fmaxf(d * A3.x + bb.z, 0.0f), r7 = fmaxf(d * A3.y + bb.w, 0.0f);
    h1v[(size_t)node * 16 + ql] =
        uint4{pack_bf2(r0, r1), pack_bf2(r2, r3), pack_bf2(r4, r5), pack_bf2(r6, r7)};
}

__global__ __launch_bounds__(256) void agg2_lsm_kernel(
    const uint2* __restrict__ g2v, const int* __restrict__ row_ptr,
    const int* __restrict__ csr_src, const float* __restrict__ dinv,
    const float4* __restrict__ b2v, float4* __restrict__ outv) {
    int tid = threadIdx.x;
    int wv = tid >> 6;
    int lane = tid & 63;
    int qt = lane >> 4;
    int ql = lane & 15;
    int node = blockIdx.x * 16 + wv * 4 + qt;
    uint2 u = g2v[(size_t)node * 16 + ql];
    f2v A0 = bfpair(u.x), A1 = bfpair(u.y);
    int e = row_ptr[node], end = row_ptr[node + 1];
#define GA2(j) g2v[(size_t)(j) * 16 + ql]
#define ACCV(v) do { A0 += bfpair((v).x); A1 += bfpair((v).y); } while (0)
    if (e + 8 <= end) {
        int j0 = csr_src[e], j1 = csr_src[e + 1], j2 = csr_src[e + 2], j3 = csr_src[e + 3];
        int j4 = csr_src[e + 4], j5 = csr_src[e + 5], j6 = csr_src[e + 6], j7 = csr_src[e + 7];
        uint2 v0 = GA2(j0), v1 = GA2(j1), v2 = GA2(j2), v3 = GA2(j3);
        uint2 v4 = GA2(j4), v5 = GA2(j5), v6 = GA2(j6), v7 = GA2(j7);
        e += 8;
        for (; e + 8 <= end; e += 8) {
            int k0 = csr_src[e], k1 = csr_src[e + 1], k2 = csr_src[e + 2], k3 = csr_src[e + 3];
            int k4 = csr_src[e + 4], k5 = csr_src[e + 5], k6 = csr_src[e + 6], k7 = csr_src[e + 7];
            ACCV(v0); ACCV(v1); ACCV(v2); ACCV(v3);
            ACCV(v4); ACCV(v5); ACCV(v6); ACCV(v7);
            v0 = GA2(k0); v1 = GA2(k1); v2 = GA2(k2); v3 = GA2(k3);
            v4 = GA2(k4); v5 = GA2(k5); v6 = GA2(k6); v7 = GA2(k7);
        }
        ACCV(v0); ACCV(v1); ACCV(v2); ACCV(v3);
        ACCV(v4); ACCV(v5); ACCV(v6); ACCV(v7);
    }
    for (; e < end; ++e) {
        uint2 v = GA2(csr_src[e]);
        ACCV(v);
    }
#undef ACCV
#undef GA2
    float d = dinv[node];
    float4 b = b2v[ql];
    float v0 = d * A0.x + b.x;
    float v1 = d * A0.y + b.y;
    float v2 = d * A1.x + b.z;
    float v3 = d * A1.y + b.w;
    float m = fmaxf(fmaxf(v0, v1), fmaxf(v2, v3));
#pragma unroll
    for (int o = 8; o > 0; o >>= 1) m = fmaxf(m, __shfl_xor(m, o, 64));
    float s = __expf(v0 - m) + __expf(v1 - m) + __expf(v2 - m) + __expf(v3 - m);
#pragma unroll
    for (int o = 8; o > 0; o >>= 1) s += __shfl_xor(s, o, 64);
    float ls = m + __logf(s);
    outv[(size_t)node * 16 + ql] = float4{v0 - ls, v1 - ls, v2 - ls, v3 - ls};
}

// ---------------- launch ----------------

extern "C" void kernel_launch(void* const* d_in, const int* in_sizes, int n_in,
                              void* d_out, int out_size, void* d_ws, size_t ws_size,
                              hipStream_t stream) {
    const float* x  = (const float*)d_in[0];
    const int* eidx = (const int*)d_in[1];
    const float* W1 = (const float*)d_in[2];
    const float* b1 = (const float*)d_in[3];
    const float* W2 = (const float*)d_in[4];
    const float* b2 = (const float*)d_in[5];
    float* out = (float*)d_out;
    const int* src = eidx;
    const int* dst = eidx + N_EDGES;

    char* base = (char*)d_ws;
    size_t off = 0;
    auto alloc = [&](size_t bytes) -> void* {
        void* p = base + off;
        off += (bytes + 255) & ~(size_t)255;
        return p;
    };
    // zero-init: ovcnt only (cnt_t fully written by partition; no gcur anymore)
    int* zbase    = (int*)alloc((size_t)64 * 4);
    int* ovcnt    = zbase;
    int* cnt_t    = (int*)alloc((size_t)NBUK * NBLK_A * 4);          // 200 KB, bucket-major
    int* bucket_base = (int*)alloc((size_t)(NBUK + 1) * 4);
    int* row_ptr  = (int*)alloc((size_t)(N_NODES + 1) * 4);
    float* dinv   = (float*)alloc((size_t)N_NODES * 4);
    unsigned* staging = (unsigned*)alloc((size_t)NBLK_A * SEGW * 4); // 12.85 MB per-block segments
    unsigned long long* ovbuf = (unsigned long long*)alloc((size_t)OV_CAP * 8);
    int* csr_src  = (int*)alloc((size_t)N_EDGES * 4);
    unsigned short* Wt1 = (unsigned short*)alloc((size_t)F_HID * F_IN * 2);
    unsigned short* Wt2 = (unsigned short*)alloc((size_t)F_OUT * F_HID * 2);
    unsigned short* g1  = (unsigned short*)alloc((size_t)N_NODES * F_HID * 2);
    unsigned short* h1  = (unsigned short*)alloc((size_t)N_NODES * F_HID * 2);
    unsigned short* g2  = g1;  // g1 dead after agg1

    hipMemsetAsync(zbase, 0, (size_t)64 * 4, stream);
    partition_kernel<<<NBLK_A, 256, 0, stream>>>(src, dst, staging, cnt_t, ovbuf, ovcnt);
    bucket_scan_kernel<<<1, 128, 0, stream>>>(cnt_t, ovbuf, ovcnt, bucket_base, row_ptr);
    deg_hist_row_kernel<<<NBUK, 256, 0, stream>>>(staging, cnt_t, ovbuf, ovcnt,
                                                  bucket_base, row_ptr, dinv);
    fill_kernel<<<NBUK * FILL_SPLIT, 256, 0, stream>>>(staging, cnt_t, row_ptr, csr_src,
                                                       ovbuf, ovcnt);
    transpose_w_kernel<<<(F_HID * F_IN + F_OUT * F_HID + 255) / 256, 256, 0, stream>>>(
        W1, W2, Wt1, Wt2);

    int gblocks = (N_NODES + 127) / 128;  // 782
    gemm_lds_kernel<F_HID, F_IN, false><<<gblocks, 256, 0, stream>>>(
        (const void*)x, Wt1, dinv, g1, N_NODES);
    agg1_kernel<<<N_NODES / 16, 256, 0, stream>>>(
        (const uint4*)g1, row_ptr, csr_src, dinv, (const float4*)b1, (uint4*)h1);

    gemm_lds_kernel<F_OUT, F_HID, true><<<gblocks, 256, 0, stream>>>(
        (const void*)h1, Wt2, dinv, g2, N_NODES);
    agg2_lsm_kernel<<<N_NODES / 16, 256, 0, stream>>>(
        (const uint2*)g2, row_ptr, csr_src, dinv, (const float4*)b2, (float4*)out);
}